// Round 1
// baseline (343.608 us; speedup 1.0000x reference)
//
#include <hip/hip_runtime.h>
#include <stdint.h>

#define B_    4
#define NQ_   2048
#define NK_   2048
#define CQ_   1024
#define CK_   768
#define H_    16
#define D_    64
#define SCALE 0.125f   // 1/sqrt(64)

typedef __attribute__((ext_vector_type(8))) short bf16x8;
typedef __attribute__((ext_vector_type(4))) float f32x4;

#define MFMA16(a, b, c) __builtin_amdgcn_mfma_f32_16x16x32_bf16((a), (b), (c), 0, 0, 0)

// async global->LDS, 16B per lane; LDS dest = wave-uniform base + lane*16
#define GLL16(gp, lp)                                                                 \
    __builtin_amdgcn_global_load_lds(                                                 \
        (__attribute__((address_space(1))) uint32_t*)(uintptr_t)(gp),                 \
        (__attribute__((address_space(3))) uint32_t*)(uintptr_t)(lp), 16, 0, 0)

__device__ inline unsigned short f2bf(float f) {
    union { float f; uint32_t u; } v; v.f = f;
    uint32_t u = v.u;
    return (unsigned short)((u + 0x7fffu + ((u >> 16) & 1u)) >> 16);
}

// ---------------------------------------------------------------- LayerNorm
template <int W>
__global__ __launch_bounds__(256) void ln_bf16(const float* __restrict__ x,
                                               const float* __restrict__ gamma,
                                               const float* __restrict__ beta,
                                               unsigned short* __restrict__ out) {
    int row = blockIdx.x;
    int tid = threadIdx.x;
    int col = tid * 4;
    const float* xr = x + (size_t)row * W;
    float v0 = 0.f, v1 = 0.f, v2 = 0.f, v3 = 0.f;
    float s = 0.f, s2 = 0.f;
    bool active = (col < W);
    if (active) {
        float4 vv = *(const float4*)(xr + col);
        v0 = vv.x; v1 = vv.y; v2 = vv.z; v3 = vv.w;
        s = v0 + v1 + v2 + v3;
        s2 = v0 * v0 + v1 * v1 + v2 * v2 + v3 * v3;
    }
    for (int off = 32; off >= 1; off >>= 1) {
        s += __shfl_xor(s, off);
        s2 += __shfl_xor(s2, off);
    }
    __shared__ float red[8];
    __shared__ float stat[2];
    int wid = tid >> 6, lane = tid & 63;
    if (lane == 0) { red[wid] = s; red[4 + wid] = s2; }
    __syncthreads();
    if (tid == 0) {
        float ts = red[0] + red[1] + red[2] + red[3];
        float ts2 = red[4] + red[5] + red[6] + red[7];
        float mu = ts / (float)W;
        float var = ts2 / (float)W - mu * mu;
        stat[0] = mu;
        stat[1] = rsqrtf(var + 1e-5f);
    }
    __syncthreads();
    float mu = stat[0], rstd = stat[1];
    if (active) {
        float4 g = *(const float4*)(gamma + col);
        float4 b = *(const float4*)(beta + col);
        ushort4 o;
        o.x = f2bf((v0 - mu) * rstd * g.x + b.x);
        o.y = f2bf((v1 - mu) * rstd * g.y + b.y);
        o.z = f2bf((v2 - mu) * rstd * g.z + b.z);
        o.w = f2bf((v3 - mu) * rstd * g.w + b.w);
        *(ushort4*)(out + (size_t)row * W + col) = o;
    }
}

// -------------------------------------------------- weight transpose + cast
// in: fp32 [K][N] row-major; out: bf16 [N][K]
__global__ __launch_bounds__(256) void transpose_cast(const float* __restrict__ Wsrc,
                                                      unsigned short* __restrict__ Wt,
                                                      int K, int N) {
    __shared__ float t[32][33];
    int n0 = blockIdx.x * 32, k0 = blockIdx.y * 32;
    int tx = threadIdx.x, ty = threadIdx.y;  // 32 x 8
    for (int i = 0; i < 4; i++)
        t[ty + 8 * i][tx] = Wsrc[(size_t)(k0 + ty + 8 * i) * N + n0 + tx];
    __syncthreads();
    for (int i = 0; i < 4; i++)
        Wt[(size_t)(n0 + ty + 8 * i) * K + k0 + tx] = f2bf(t[tx][ty + 8 * i]);
}

// ------------------------------------------------------------------- GEMM
// Y[M=8192][1024] = X[M][Kd] @ Wt[1024][Kd]^T + bias
// MODE 0: bf16 out remapped [b][h][n][64]   (Q / K)
// MODE 1: bf16 out remapped [b][h][64][nk]  (V transposed)
// MODE 2: fp32 out plain [M][1024]          (final O)
template <int MODE>
__global__ __launch_bounds__(256) void gemm_bt(const unsigned short* __restrict__ X,
                                               const unsigned short* __restrict__ Wt,
                                               const float* __restrict__ bias,
                                               void* __restrict__ outp, int Kd) {
    __shared__ __align__(16) unsigned short As[128 * 64];
    __shared__ __align__(16) unsigned short Bs[128 * 64];
    int tid = threadIdx.x;
    int lane = tid & 63, wid = tid >> 6;
    int m0 = blockIdx.y * 128, n0 = blockIdx.x * 128;
    int wm = wid >> 1, wn = wid & 1;

    f32x4 acc[4][4];
    for (int i = 0; i < 4; i++)
        for (int j = 0; j < 4; j++) acc[i][j] = (f32x4){0.f, 0.f, 0.f, 0.f};

    int srow = wid * 8 + (lane >> 3);                       // staging row (mod 32-chunk)
    int sxor = ((lane & 7) * 16) ^ (((lane >> 3) & 7) << 4);  // pre-swizzled col byte
    int swz = (lane & 7) << 4;                              // read-side swizzle
    const char* Xb = (const char*)X;
    const char* Wb = (const char*)Wt;
    char* AsB = (char*)As;
    char* BsB = (char*)Bs;

    for (int k0 = 0; k0 < Kd; k0 += 64) {
        for (int i = 0; i < 4; i++) {
            int row = i * 32 + srow;
            GLL16(Xb + ((size_t)(m0 + row) * Kd + k0) * 2 + sxor, AsB + i * 4096 + wid * 1024);
            GLL16(Wb + ((size_t)(n0 + row) * Kd + k0) * 2 + sxor, BsB + i * 4096 + wid * 1024);
        }
        __syncthreads();
        for (int kk = 0; kk < 2; kk++) {
            int cb = (((lane >> 4) * 16 + kk * 64) ^ swz);
            bf16x8 a[4], b[4];
            for (int mf = 0; mf < 4; mf++)
                a[mf] = *(const bf16x8*)(AsB + (wm * 64 + mf * 16 + (lane & 15)) * 128 + cb);
            for (int nf = 0; nf < 4; nf++)
                b[nf] = *(const bf16x8*)(BsB + (wn * 64 + nf * 16 + (lane & 15)) * 128 + cb);
            for (int mf = 0; mf < 4; mf++)
                for (int nf = 0; nf < 4; nf++) acc[mf][nf] = MFMA16(a[mf], b[nf], acc[mf][nf]);
        }
        __syncthreads();
    }

    int crow0 = m0 + wm * 64;
    int ccol0 = n0 + wn * 64;
    for (int nf = 0; nf < 4; nf++) {
        int col = ccol0 + nf * 16 + (lane & 15);
        float bv = bias[col];
        for (int mf = 0; mf < 4; mf++) {
            int rowb = crow0 + mf * 16 + (lane >> 4) * 4;
            for (int r = 0; r < 4; r++) {
                int row = rowb + r;
                float val = acc[mf][nf][r] + bv;
                if (MODE == 2) {
                    ((float*)outp)[(size_t)row * 1024 + col] = val;
                } else {
                    int b = row >> 11, nq = row & 2047;
                    int h = col >> 6, d = col & 63;
                    unsigned short bfv = f2bf(val);
                    if (MODE == 0)
                        ((unsigned short*)outp)[(((size_t)(b * H_ + h)) * NQ_ + nq) * 64 + d] = bfv;
                    else
                        ((unsigned short*)outp)[(((size_t)(b * H_ + h)) * 64 + d) * NK_ + nq] = bfv;
                }
            }
        }
    }
}

// --------------------------------------------------------- flash attention
// Q,K: [B*H][2048][64] bf16 ; Vt: [B*H][64][2048] bf16
// out attended: [B*NQ][1024] bf16
__global__ __launch_bounds__(256) void flash_attn(const unsigned short* __restrict__ Q,
                                                  const unsigned short* __restrict__ K,
                                                  const unsigned short* __restrict__ Vt,
                                                  unsigned short* __restrict__ attended) {
    __shared__ __align__(16) char smem[8192 * 2 + 4 * 2304];
    char* Ks = smem;
    char* Vs = smem + 8192;
    int tid = threadIdx.x, lane = tid & 63, wid = tid >> 6;
    char* Ps = smem + 16384 + wid * 2304;  // per-wave P tile [16][72] bf16

    int bh = blockIdx.y;
    int q0 = blockIdx.x * 64;
    const char* Qb = (const char*)(Q + (size_t)bh * NQ_ * 64);
    const char* Kb = (const char*)(K + (size_t)bh * NK_ * 64);
    const char* Vb = (const char*)(Vt + (size_t)bh * 64 * NK_);

    // Q fragments, held for the whole kernel
    int qrow = q0 + wid * 16 + (lane & 15);
    bf16x8 qf[2];
    qf[0] = *(const bf16x8*)(Qb + (size_t)qrow * 128 + (lane >> 4) * 16);
    qf[1] = *(const bf16x8*)(Qb + (size_t)qrow * 128 + (lane >> 4) * 16 + 64);

    f32x4 acc[4];
    for (int i = 0; i < 4; i++) acc[i] = (f32x4){0.f, 0.f, 0.f, 0.f};
    float mst[4] = {-3.0e38f, -3.0e38f, -3.0e38f, -3.0e38f};
    float lst[4] = {0.f, 0.f, 0.f, 0.f};

    int srow = wid * 16 + (lane >> 3);                       // staging row base
    int sxor = ((lane & 7) * 16) ^ (((lane >> 3) & 7) << 4); // pre-swizzled src col
    int cb0 = (lane >> 4) * 16;
    int swz = (lane & 7) << 4;
    ushort* Pw = (ushort*)Ps;

    for (int nk0 = 0; nk0 < NK_; nk0 += 64) {
        for (int c = 0; c < 2; c++) {
            int row = srow + c * 8;
            GLL16(Kb + (size_t)(nk0 + row) * 128 + sxor, Ks + wid * 2048 + c * 1024);
            GLL16(Vb + (size_t)row * 4096 + nk0 * 2 + sxor, Vs + wid * 2048 + c * 1024);
        }
        __syncthreads();

        // S = Q K^T  (raw, scale folded into exp)
        f32x4 s[4];
        for (int nf = 0; nf < 4; nf++) {
            s[nf] = (f32x4){0.f, 0.f, 0.f, 0.f};
            for (int kk = 0; kk < 2; kk++) {
                bf16x8 b = *(const bf16x8*)(Ks + (nf * 16 + (lane & 15)) * 128 + ((cb0 + kk * 64) ^ swz));
                s[nf] = MFMA16(qf[kk], b, s[nf]);
            }
        }

        // online softmax (rows r: row = (lane>>4)*4 + r)
        float mloc[4];
        for (int r = 0; r < 4; r++)
            mloc[r] = fmaxf(fmaxf(s[0][r], s[1][r]), fmaxf(s[2][r], s[3][r]));
        for (int off = 1; off < 16; off <<= 1)
            for (int r = 0; r < 4; r++) mloc[r] = fmaxf(mloc[r], __shfl_xor(mloc[r], off));
        float alpha[4];
        for (int r = 0; r < 4; r++) {
            float mn = fmaxf(mst[r], mloc[r]);
            alpha[r] = __expf((mst[r] - mn) * SCALE);
            mst[r] = mn;
        }
        for (int df = 0; df < 4; df++)
            for (int r = 0; r < 4; r++) acc[df][r] *= alpha[r];
        float psum[4] = {0.f, 0.f, 0.f, 0.f};
        for (int nf = 0; nf < 4; nf++)
            for (int r = 0; r < 4; r++) {
                float p = __expf((s[nf][r] - mst[r]) * SCALE);
                psum[r] += p;
                Pw[((lane >> 4) * 4 + r) * 72 + (lane & 15) + 16 * nf] = f2bf(p);
            }
        for (int off = 1; off < 16; off <<= 1)
            for (int r = 0; r < 4; r++) psum[r] += __shfl_xor(psum[r], off);
        for (int r = 0; r < 4; r++) lst[r] = lst[r] * alpha[r] + psum[r];

        // O += P V
        for (int kk = 0; kk < 2; kk++) {
            bf16x8 ap = *(const bf16x8*)(Ps + (lane & 15) * 144 + cb0 + kk * 64);
            for (int df = 0; df < 4; df++) {
                bf16x8 bv = *(const bf16x8*)(Vs + (df * 16 + (lane & 15)) * 128 + ((cb0 + kk * 64) ^ swz));
                acc[df] = MFMA16(ap, bv, acc[df]);
            }
        }
        __syncthreads();
    }

    int b = bh >> 4, h = bh & 15;
    for (int df = 0; df < 4; df++)
        for (int r = 0; r < 4; r++) {
            int row = q0 + wid * 16 + (lane >> 4) * 4 + r;
            int col = h * 64 + df * 16 + (lane & 15);
            attended[(size_t)(b * NQ_ + row) * CQ_ + col] = f2bf(acc[df][r] / lst[r]);
        }
}

// ---------------------------------------------------------------- launcher
extern "C" void kernel_launch(void* const* d_in, const int* in_sizes, int n_in,
                              void* d_out, int out_size, void* d_ws, size_t ws_size,
                              hipStream_t stream) {
    const float* qt  = (const float*)d_in[0];
    const float* ct  = (const float*)d_in[1];
    const float* Wq  = (const float*)d_in[2];
    const float* bq  = (const float*)d_in[3];
    const float* Wk  = (const float*)d_in[4];
    const float* bk  = (const float*)d_in[5];
    const float* Wv  = (const float*)d_in[6];
    const float* bv  = (const float*)d_in[7];
    const float* Wo  = (const float*)d_in[8];
    const float* bo  = (const float*)d_in[9];
    const float* gq  = (const float*)d_in[10];
    const float* btq = (const float*)d_in[11];
    const float* gc  = (const float*)d_in[12];
    const float* btc = (const float*)d_in[13];

    char* ws = (char*)d_ws;
    unsigned short* xq  = (unsigned short*)(ws + 0);         // 16 MB (reused as attended)
    unsigned short* xc  = (unsigned short*)(ws + 16777216);  // 12 MB
    unsigned short* Wqt = (unsigned short*)(ws + 29360128);  // 2 MB
    unsigned short* Wkt = (unsigned short*)(ws + 31457280);  // 1.5 MB
    unsigned short* Wvt = (unsigned short*)(ws + 33030144);  // 1.5 MB
    unsigned short* Wot = (unsigned short*)(ws + 34603008);  // 2 MB
    unsigned short* Qb  = (unsigned short*)(ws + 36700160);  // 16 MB
    unsigned short* Kb  = (unsigned short*)(ws + 53477376);  // 16 MB
    unsigned short* Vtb = (unsigned short*)(ws + 70254592);  // 16 MB  (total ~83 MB)

    ln_bf16<1024><<<8192, 256, 0, stream>>>(qt, gq, btq, xq);
    ln_bf16<768><<<8192, 256, 0, stream>>>(ct, gc, btc, xc);

    transpose_cast<<<dim3(32, 32), dim3(32, 8), 0, stream>>>(Wq, Wqt, 1024, 1024);
    transpose_cast<<<dim3(32, 24), dim3(32, 8), 0, stream>>>(Wk, Wkt, 768, 1024);
    transpose_cast<<<dim3(32, 24), dim3(32, 8), 0, stream>>>(Wv, Wvt, 768, 1024);
    transpose_cast<<<dim3(32, 32), dim3(32, 8), 0, stream>>>(Wo, Wot, 1024, 1024);

    gemm_bt<0><<<dim3(8, 64), 256, 0, stream>>>(xq, Wqt, bq, Qb, 1024);
    gemm_bt<0><<<dim3(8, 64), 256, 0, stream>>>(xc, Wkt, bk, Kb, 768);
    gemm_bt<1><<<dim3(8, 64), 256, 0, stream>>>(xc, Wvt, bv, Vtb, 768);

    flash_attn<<<dim3(32, 64), 256, 0, stream>>>(Qb, Kb, Vtb, xq);

    gemm_bt<2><<<dim3(8, 64), 256, 0, stream>>>(xq, Wot, bo, d_out, 1024);
}

// Round 3
// 264.358 us; speedup vs baseline: 1.2998x; 1.2998x over previous
//
#include <hip/hip_runtime.h>
#include <hip/hip_bf16.h>
#include <stdint.h>

#define B_    4
#define NQ_   2048
#define NK_   2048
#define CQ_   1024
#define CK_   768
#define H_    16
#define D_    64
#define SCALE 0.125f   // 1/sqrt(64)
#define C2    0.1803368801111204f  // SCALE * log2(e)

typedef __attribute__((ext_vector_type(8))) short bf16x8;
typedef __attribute__((ext_vector_type(4))) float f32x4;

#define MFMA16(a, b, c) __builtin_amdgcn_mfma_f32_16x16x32_bf16((a), (b), (c), 0, 0, 0)

// async global->LDS, 16B per lane; LDS dest = wave-uniform base + lane*16
#define GLL16(gp, lp)                                                                 \
    __builtin_amdgcn_global_load_lds(                                                 \
        (__attribute__((address_space(1))) uint32_t*)(uintptr_t)(gp),                 \
        (__attribute__((address_space(3))) uint32_t*)(uintptr_t)(lp), 16, 0, 0)

__device__ inline unsigned short f2bf(float f) {
    union { float f; uint32_t u; } v; v.f = f;
    uint32_t u = v.u;
    return (unsigned short)((u + 0x7fffu + ((u >> 16) & 1u)) >> 16);
}

__device__ inline uint32_t packbf2(float a, float b) {
    union { __hip_bfloat162 h; uint32_t u; } v;
    v.h = __float22bfloat162_rn(float2{a, b});
    return v.u;
}

// ---------------------------------------------------------------- LayerNorm
template <int W>
__global__ __launch_bounds__(256) void ln_bf16(const float* __restrict__ x,
                                               const float* __restrict__ gamma,
                                               const float* __restrict__ beta,
                                               unsigned short* __restrict__ out) {
    int row = blockIdx.x;
    int tid = threadIdx.x;
    int col = tid * 4;
    const float* xr = x + (size_t)row * W;
    float v0 = 0.f, v1 = 0.f, v2 = 0.f, v3 = 0.f;
    float s = 0.f, s2 = 0.f;
    bool active = (col < W);
    if (active) {
        float4 vv = *(const float4*)(xr + col);
        v0 = vv.x; v1 = vv.y; v2 = vv.z; v3 = vv.w;
        s = v0 + v1 + v2 + v3;
        s2 = v0 * v0 + v1 * v1 + v2 * v2 + v3 * v3;
    }
    for (int off = 32; off >= 1; off >>= 1) {
        s += __shfl_xor(s, off);
        s2 += __shfl_xor(s2, off);
    }
    __shared__ float red[8];
    __shared__ float stat[2];
    int wid = tid >> 6, lane = tid & 63;
    if (lane == 0) { red[wid] = s; red[4 + wid] = s2; }
    __syncthreads();
    if (tid == 0) {
        float ts = red[0] + red[1] + red[2] + red[3];
        float ts2 = red[4] + red[5] + red[6] + red[7];
        float mu = ts / (float)W;
        float var = ts2 / (float)W - mu * mu;
        stat[0] = mu;
        stat[1] = rsqrtf(var + 1e-5f);
    }
    __syncthreads();
    float mu = stat[0], rstd = stat[1];
    if (active) {
        float4 g = *(const float4*)(gamma + col);
        float4 b = *(const float4*)(beta + col);
        ushort4 o;
        o.x = f2bf((v0 - mu) * rstd * g.x + b.x);
        o.y = f2bf((v1 - mu) * rstd * g.y + b.y);
        o.z = f2bf((v2 - mu) * rstd * g.z + b.z);
        o.w = f2bf((v3 - mu) * rstd * g.w + b.w);
        *(ushort4*)(out + (size_t)row * W + col) = o;
    }
}

// -------------------------------------------------- weight transpose + cast
__global__ __launch_bounds__(256) void transpose_cast(const float* __restrict__ Wsrc,
                                                      unsigned short* __restrict__ Wt,
                                                      int K, int N) {
    __shared__ float t[32][33];
    int n0 = blockIdx.x * 32, k0 = blockIdx.y * 32;
    int tx = threadIdx.x, ty = threadIdx.y;  // 32 x 8
    for (int i = 0; i < 4; i++)
        t[ty + 8 * i][tx] = Wsrc[(size_t)(k0 + ty + 8 * i) * N + n0 + tx];
    __syncthreads();
    for (int i = 0; i < 4; i++)
        Wt[(size_t)(n0 + ty + 8 * i) * K + k0 + tx] = f2bf(t[tx][ty + 8 * i]);
}

// ------------------------------------------------------------------- GEMM
// Y[M=8192][1024] = X[M][Kd] @ Wt[1024][Kd]^T + bias
// MODE 0: bf16 out remapped [b][h][n][64]   (Q / K)
// MODE 1: bf16 out remapped [b][h][64][nk]  (V transposed)
// MODE 2: fp32 out plain [M][1024]          (final O)
template <int MODE>
__global__ __launch_bounds__(256) void gemm_bt(const unsigned short* __restrict__ X,
                                               const unsigned short* __restrict__ Wt,
                                               const float* __restrict__ bias,
                                               void* __restrict__ outp, int Kd) {
    __shared__ __align__(16) unsigned short As[128 * 64];
    __shared__ __align__(16) unsigned short Bs[128 * 64];
    int tid = threadIdx.x;
    int lane = tid & 63, wid = tid >> 6;
    int m0 = blockIdx.y * 128, n0 = blockIdx.x * 128;
    int wm = wid >> 1, wn = wid & 1;

    f32x4 acc[4][4];
    for (int i = 0; i < 4; i++)
        for (int j = 0; j < 4; j++) acc[i][j] = (f32x4){0.f, 0.f, 0.f, 0.f};

    int srow = wid * 8 + (lane >> 3);
    int sxor = ((lane & 7) * 16) ^ (((lane >> 3) & 7) << 4);
    int swz = (lane & 7) << 4;
    const char* Xb = (const char*)X;
    const char* Wb = (const char*)Wt;
    char* AsB = (char*)As;
    char* BsB = (char*)Bs;

    for (int k0 = 0; k0 < Kd; k0 += 64) {
        for (int i = 0; i < 4; i++) {
            int row = i * 32 + srow;
            GLL16(Xb + ((size_t)(m0 + row) * Kd + k0) * 2 + sxor, AsB + i * 4096 + wid * 1024);
            GLL16(Wb + ((size_t)(n0 + row) * Kd + k0) * 2 + sxor, BsB + i * 4096 + wid * 1024);
        }
        __syncthreads();
        for (int kk = 0; kk < 2; kk++) {
            int cb = (((lane >> 4) * 16 + kk * 64) ^ swz);
            bf16x8 a[4], b[4];
            for (int mf = 0; mf < 4; mf++)
                a[mf] = *(const bf16x8*)(AsB + (wm * 64 + mf * 16 + (lane & 15)) * 128 + cb);
            for (int nf = 0; nf < 4; nf++)
                b[nf] = *(const bf16x8*)(BsB + (wn * 64 + nf * 16 + (lane & 15)) * 128 + cb);
            for (int mf = 0; mf < 4; mf++)
                for (int nf = 0; nf < 4; nf++) acc[mf][nf] = MFMA16(a[mf], b[nf], acc[mf][nf]);
        }
        __syncthreads();
    }

    int crow0 = m0 + wm * 64;
    int ccol0 = n0 + wn * 64;
    for (int nf = 0; nf < 4; nf++) {
        int col = ccol0 + nf * 16 + (lane & 15);
        float bv = bias[col];
        for (int mf = 0; mf < 4; mf++) {
            int rowb = crow0 + mf * 16 + (lane >> 4) * 4;
            for (int r = 0; r < 4; r++) {
                int row = rowb + r;
                float val = acc[mf][nf][r] + bv;
                if (MODE == 2) {
                    ((float*)outp)[(size_t)row * 1024 + col] = val;
                } else {
                    int b = row >> 11, nq = row & 2047;
                    int h = col >> 6, d = col & 63;
                    unsigned short bfv = f2bf(val);
                    if (MODE == 0)
                        ((unsigned short*)outp)[(((size_t)(b * H_ + h)) * NQ_ + nq) * 64 + d] = bfv;
                    else
                        ((unsigned short*)outp)[(((size_t)(b * H_ + h)) * 64 + d) * NK_ + nq] = bfv;
                }
            }
        }
    }
}

// --------------------------------------------------------- flash attention
// Q,K: [B*H][2048][64] bf16 ; Vt: [B*H][64][2048] bf16 (plain layout)
// out attended: [B*NQ][1024] bf16
// Swapped QK^T: S^T = mfma(K,Q) -> lane holds q=lane&15, keys {nf*16+4g+r}.
// Softmax fully in-register (2 shuffles per reduce), defer-max rescale.
// P routed through a per-wave LDS tile [16][72] with round-1's verified
// write->read pattern; V unpermuted.
__global__ __launch_bounds__(256) void flash_attn(const unsigned short* __restrict__ Q,
                                                  const unsigned short* __restrict__ K,
                                                  const unsigned short* __restrict__ Vt,
                                                  unsigned short* __restrict__ attended) {
    __shared__ __align__(16) char smem[2][16384];            // [buf][ K 8KB | V 8KB ]
    __shared__ __align__(16) unsigned short Ps[4][2][16 * 72];  // per-wave, parity-rotated
    int tid = threadIdx.x, lane = tid & 63, wid = tid >> 6;
    int g = lane >> 4;

    int bh = blockIdx.y;
    int q0 = blockIdx.x * 64;
    const char* Qb = (const char*)(Q + (size_t)bh * NQ_ * 64);
    const char* Kb = (const char*)(K + (size_t)bh * NK_ * 64);
    const char* Vb = (const char*)(Vt + (size_t)bh * 64 * NK_);

    // Q fragments (B-operand of swapped QK^T), held for the whole kernel
    int qrow = q0 + wid * 16 + (lane & 15);
    bf16x8 qf[2];
    qf[0] = *(const bf16x8*)(Qb + (size_t)qrow * 128 + g * 16);
    qf[1] = *(const bf16x8*)(Qb + (size_t)qrow * 128 + g * 16 + 64);

    f32x4 acc[4];
    for (int i = 0; i < 4; i++) acc[i] = (f32x4){0.f, 0.f, 0.f, 0.f};
    float mst = -3.0e38f;
    float lst = 0.f;

    int srow = wid * 16 + (lane >> 3);
    int sxor = ((lane & 7) * 16) ^ (((lane >> 3) & 7) << 4);
    int cb0 = g * 16;
    int swz = (lane & 7) << 4;

    auto STAGE = [&](int buf, int nk0) {
        char* Ksb = smem[buf];
        char* Vsb = smem[buf] + 8192;
#pragma unroll
        for (int c = 0; c < 2; c++) {
            int row = srow + c * 8;
            GLL16(Kb + (size_t)(nk0 + row) * 128 + sxor, Ksb + wid * 2048 + c * 1024);
            GLL16(Vb + (size_t)row * 4096 + nk0 * 2 + sxor, Vsb + wid * 2048 + c * 1024);
        }
    };

    STAGE(0, 0);
    __syncthreads();
    int cur = 0;

    for (int t = 0; t < NK_ / 64; ++t) {
        if (t + 1 < NK_ / 64) STAGE(cur ^ 1, (t + 1) * 64);
        const char* Ksb = smem[cur];
        const char* Vsb = smem[cur] + 8192;

        // S^T = K Q^T : lane holds q = lane&15, key = nf*16 + 4g + r
        f32x4 s[4];
#pragma unroll
        for (int nf = 0; nf < 4; nf++) {
            s[nf] = (f32x4){0.f, 0.f, 0.f, 0.f};
#pragma unroll
            for (int kk = 0; kk < 2; kk++) {
                bf16x8 kf = *(const bf16x8*)(Ksb + (nf * 16 + (lane & 15)) * 128 + ((cb0 + kk * 64) ^ swz));
                s[nf] = MFMA16(kf, qf[kk], s[nf]);
            }
        }

        // online softmax over the lane's 16 keys + cross-replica reduce
        float mloc = s[0][0];
#pragma unroll
        for (int nf = 0; nf < 4; nf++)
#pragma unroll
            for (int r = 0; r < 4; r++) mloc = fmaxf(mloc, s[nf][r]);
        mloc = fmaxf(mloc, __shfl_xor(mloc, 16));
        mloc = fmaxf(mloc, __shfl_xor(mloc, 32));

        // defer-max: rescale only when max grew enough to matter (P <= 2^8)
        if (!__all(mloc - mst <= 44.36f)) {
            float mnew = fmaxf(mst, mloc);
            float alpha = __builtin_amdgcn_exp2f((mst - mnew) * C2);
            mst = mnew;
            lst *= alpha;
            float al[4];
#pragma unroll
            for (int r = 0; r < 4; r++) al[r] = __shfl(alpha, 4 * g + r);
#pragma unroll
            for (int df = 0; df < 4; df++)
#pragma unroll
                for (int r = 0; r < 4; r++) acc[df][r] *= al[r];
        }

        float mc = mst * C2;
        float p[4][4];
        float psum = 0.f;
#pragma unroll
        for (int nf = 0; nf < 4; nf++)
#pragma unroll
            for (int r = 0; r < 4; r++) {
                float e = __builtin_amdgcn_exp2f(s[nf][r] * C2 - mc);
                p[nf][r] = e;
                psum += e;
            }
        psum += __shfl_xor(psum, 16);
        psum += __shfl_xor(psum, 32);
        lst += psum;

        // write P[q][key] to per-wave LDS: ushort idx = q*72 + (16nf + 4g + r)
        unsigned short* Pw = Ps[wid][t & 1];
        uint32_t* P32 = (uint32_t*)Pw;
        int wbase = (lane & 15) * 36 + g * 2;
#pragma unroll
        for (int nf = 0; nf < 4; nf++) {
            P32[wbase + nf * 8]     = packbf2(p[nf][0], p[nf][1]);
            P32[wbase + nf * 8 + 1] = packbf2(p[nf][2], p[nf][3]);
        }

        // O^acc += P V : A-frag = P[q=lane&15][keys 8g+32kk+j] (round-1 pattern)
#pragma unroll
        for (int kk = 0; kk < 2; kk++) {
            bf16x8 ap = *(const bf16x8*)((const char*)Pw + (lane & 15) * 144 + cb0 + kk * 64);
#pragma unroll
            for (int df = 0; df < 4; df++) {
                bf16x8 bv = *(const bf16x8*)(Vsb + (df * 16 + (lane & 15)) * 128 + ((cb0 + kk * 64) ^ swz));
                acc[df] = MFMA16(ap, bv, acc[df]);
            }
        }
        __syncthreads();
        cur ^= 1;
    }

    int b = bh >> 4, h = bh & 15;
    float li[4];
#pragma unroll
    for (int r = 0; r < 4; r++) li[r] = 1.0f / __shfl(lst, 4 * g + r);
#pragma unroll
    for (int df = 0; df < 4; df++)
#pragma unroll
        for (int r = 0; r < 4; r++) {
            int row = q0 + wid * 16 + 4 * g + r;
            int col = h * 64 + df * 16 + (lane & 15);
            attended[(size_t)(b * NQ_ + row) * CQ_ + col] = f2bf(acc[df][r] * li[r]);
        }
}

// ---------------------------------------------------------------- launcher
extern "C" void kernel_launch(void* const* d_in, const int* in_sizes, int n_in,
                              void* d_out, int out_size, void* d_ws, size_t ws_size,
                              hipStream_t stream) {
    const float* qt  = (const float*)d_in[0];
    const float* ct  = (const float*)d_in[1];
    const float* Wq  = (const float*)d_in[2];
    const float* bq  = (const float*)d_in[3];
    const float* Wk  = (const float*)d_in[4];
    const float* bk  = (const float*)d_in[5];
    const float* Wv  = (const float*)d_in[6];
    const float* bv  = (const float*)d_in[7];
    const float* Wo  = (const float*)d_in[8];
    const float* bo  = (const float*)d_in[9];
    const float* gq  = (const float*)d_in[10];
    const float* btq = (const float*)d_in[11];
    const float* gc  = (const float*)d_in[12];
    const float* btc = (const float*)d_in[13];

    char* ws = (char*)d_ws;
    unsigned short* xq  = (unsigned short*)(ws + 0);         // 16 MB (reused as attended)
    unsigned short* xc  = (unsigned short*)(ws + 16777216);  // 12 MB
    unsigned short* Wqt = (unsigned short*)(ws + 29360128);  // 2 MB
    unsigned short* Wkt = (unsigned short*)(ws + 31457280);  // 1.5 MB
    unsigned short* Wvt = (unsigned short*)(ws + 33030144);  // 1.5 MB
    unsigned short* Wot = (unsigned short*)(ws + 34603008);  // 2 MB
    unsigned short* Qb  = (unsigned short*)(ws + 36700160);  // 16 MB
    unsigned short* Kb  = (unsigned short*)(ws + 53477376);  // 16 MB
    unsigned short* Vtb = (unsigned short*)(ws + 70254592);  // 16 MB  (total ~83 MB)

    ln_bf16<1024><<<8192, 256, 0, stream>>>(qt, gq, btq, xq);
    ln_bf16<768><<<8192, 256, 0, stream>>>(ct, gc, btc, xc);

    transpose_cast<<<dim3(32, 32), dim3(32, 8), 0, stream>>>(Wq, Wqt, 1024, 1024);
    transpose_cast<<<dim3(32, 24), dim3(32, 8), 0, stream>>>(Wk, Wkt, 768, 1024);
    transpose_cast<<<dim3(32, 24), dim3(32, 8), 0, stream>>>(Wv, Wvt, 768, 1024);
    transpose_cast<<<dim3(32, 32), dim3(32, 8), 0, stream>>>(Wo, Wot, 1024, 1024);

    gemm_bt<0><<<dim3(8, 64), 256, 0, stream>>>(xq, Wqt, bq, Qb, 1024);
    gemm_bt<0><<<dim3(8, 64), 256, 0, stream>>>(xc, Wkt, bk, Kb, 768);
    gemm_bt<1><<<dim3(8, 64), 256, 0, stream>>>(xc, Wvt, bv, Vtb, 768);

    flash_attn<<<dim3(32, 64), 256, 0, stream>>>(Qb, Kb, Vtb, xq);

    gemm_bt<2><<<dim3(8, 64), 256, 0, stream>>>(xq, Wot, bo, d_out, 1024);
}

// Round 4
// 238.031 us; speedup vs baseline: 1.4435x; 1.1106x over previous
//
#include <hip/hip_runtime.h>
#include <hip/hip_bf16.h>
#include <stdint.h>

#define B_    4
#define NQ_   2048
#define NK_   2048
#define CQ_   1024
#define CK_   768
#define H_    16
#define D_    64
#define SCALE 0.125f   // 1/sqrt(64)
#define C2    0.1803368801111204f  // SCALE * log2(e)

typedef __attribute__((ext_vector_type(8))) short bf16x8;
typedef __attribute__((ext_vector_type(4))) float f32x4;

#define MFMA16(a, b, c) __builtin_amdgcn_mfma_f32_16x16x32_bf16((a), (b), (c), 0, 0, 0)

// async global->LDS, 16B per lane; LDS dest = wave-uniform base + lane*16
#define GLL16(gp, lp)                                                                 \
    __builtin_amdgcn_global_load_lds(                                                 \
        (__attribute__((address_space(1))) uint32_t*)(uintptr_t)(gp),                 \
        (__attribute__((address_space(3))) uint32_t*)(uintptr_t)(lp), 16, 0, 0)

__device__ inline unsigned short f2bf(float f) {
    union { float f; uint32_t u; } v; v.f = f;
    uint32_t u = v.u;
    return (unsigned short)((u + 0x7fffu + ((u >> 16) & 1u)) >> 16);
}

__device__ inline uint32_t packbf2(float a, float b) {
    union { __hip_bfloat162 h; uint32_t u; } v;
    v.h = __float22bfloat162_rn(float2{a, b});
    return v.u;
}

// ---------------------------------------------------------------- LayerNorm
template <int W>
__global__ __launch_bounds__(256) void ln_bf16(const float* __restrict__ x,
                                               const float* __restrict__ gamma,
                                               const float* __restrict__ beta,
                                               unsigned short* __restrict__ out) {
    int row = blockIdx.x;
    int tid = threadIdx.x;
    int col = tid * 4;
    const float* xr = x + (size_t)row * W;
    float v0 = 0.f, v1 = 0.f, v2 = 0.f, v3 = 0.f;
    float s = 0.f, s2 = 0.f;
    bool active = (col < W);
    if (active) {
        float4 vv = *(const float4*)(xr + col);
        v0 = vv.x; v1 = vv.y; v2 = vv.z; v3 = vv.w;
        s = v0 + v1 + v2 + v3;
        s2 = v0 * v0 + v1 * v1 + v2 * v2 + v3 * v3;
    }
    for (int off = 32; off >= 1; off >>= 1) {
        s += __shfl_xor(s, off);
        s2 += __shfl_xor(s2, off);
    }
    __shared__ float red[8];
    __shared__ float stat[2];
    int wid = tid >> 6, lane = tid & 63;
    if (lane == 0) { red[wid] = s; red[4 + wid] = s2; }
    __syncthreads();
    if (tid == 0) {
        float ts = red[0] + red[1] + red[2] + red[3];
        float ts2 = red[4] + red[5] + red[6] + red[7];
        float mu = ts / (float)W;
        float var = ts2 / (float)W - mu * mu;
        stat[0] = mu;
        stat[1] = rsqrtf(var + 1e-5f);
    }
    __syncthreads();
    float mu = stat[0], rstd = stat[1];
    if (active) {
        float4 g = *(const float4*)(gamma + col);
        float4 b = *(const float4*)(beta + col);
        ushort4 o;
        o.x = f2bf((v0 - mu) * rstd * g.x + b.x);
        o.y = f2bf((v1 - mu) * rstd * g.y + b.y);
        o.z = f2bf((v2 - mu) * rstd * g.z + b.z);
        o.w = f2bf((v3 - mu) * rstd * g.w + b.w);
        *(ushort4*)(out + (size_t)row * W + col) = o;
    }
}

// -------------------------------------------------- weight transpose + cast
__global__ __launch_bounds__(256) void transpose_cast(const float* __restrict__ Wsrc,
                                                      unsigned short* __restrict__ Wt,
                                                      int K, int N) {
    __shared__ float t[32][33];
    int n0 = blockIdx.x * 32, k0 = blockIdx.y * 32;
    int tx = threadIdx.x, ty = threadIdx.y;  // 32 x 8
    for (int i = 0; i < 4; i++)
        t[ty + 8 * i][tx] = Wsrc[(size_t)(k0 + ty + 8 * i) * N + n0 + tx];
    __syncthreads();
    for (int i = 0; i < 4; i++)
        Wt[(size_t)(n0 + ty + 8 * i) * K + k0 + tx] = f2bf(t[tx][ty + 8 * i]);
}

// ------------------------------------------------------------------- GEMM
// Y[M=8192][1024] = X[M][Kd] @ Wt[1024][Kd]^T + bias
// MODE 0: bf16 out remapped [b][h][n][64]   (Q / K)
// MODE 1: bf16 out remapped [b][h][64][nk]  (V transposed)
// MODE 2: fp32 out plain [M][1024]          (final O)
template <int MODE>
__global__ __launch_bounds__(256) void gemm_bt(const unsigned short* __restrict__ X,
                                               const unsigned short* __restrict__ Wt,
                                               const float* __restrict__ bias,
                                               void* __restrict__ outp, int Kd) {
    __shared__ __align__(16) unsigned short As[128 * 64];
    __shared__ __align__(16) unsigned short Bs[128 * 64];
    int tid = threadIdx.x;
    int lane = tid & 63, wid = tid >> 6;
    int m0 = blockIdx.y * 128, n0 = blockIdx.x * 128;
    int wm = wid >> 1, wn = wid & 1;

    f32x4 acc[4][4];
    for (int i = 0; i < 4; i++)
        for (int j = 0; j < 4; j++) acc[i][j] = (f32x4){0.f, 0.f, 0.f, 0.f};

    int srow = wid * 8 + (lane >> 3);
    int sxor = ((lane & 7) * 16) ^ (((lane >> 3) & 7) << 4);
    int swz = (lane & 7) << 4;
    const char* Xb = (const char*)X;
    const char* Wb = (const char*)Wt;
    char* AsB = (char*)As;
    char* BsB = (char*)Bs;

    for (int k0 = 0; k0 < Kd; k0 += 64) {
        for (int i = 0; i < 4; i++) {
            int row = i * 32 + srow;
            GLL16(Xb + ((size_t)(m0 + row) * Kd + k0) * 2 + sxor, AsB + i * 4096 + wid * 1024);
            GLL16(Wb + ((size_t)(n0 + row) * Kd + k0) * 2 + sxor, BsB + i * 4096 + wid * 1024);
        }
        __syncthreads();
        for (int kk = 0; kk < 2; kk++) {
            int cb = (((lane >> 4) * 16 + kk * 64) ^ swz);
            bf16x8 a[4], b[4];
            for (int mf = 0; mf < 4; mf++)
                a[mf] = *(const bf16x8*)(AsB + (wm * 64 + mf * 16 + (lane & 15)) * 128 + cb);
            for (int nf = 0; nf < 4; nf++)
                b[nf] = *(const bf16x8*)(BsB + (wn * 64 + nf * 16 + (lane & 15)) * 128 + cb);
            for (int mf = 0; mf < 4; mf++)
                for (int nf = 0; nf < 4; nf++) acc[mf][nf] = MFMA16(a[mf], b[nf], acc[mf][nf]);
        }
        __syncthreads();
    }

    int crow0 = m0 + wm * 64;
    int ccol0 = n0 + wn * 64;
    for (int nf = 0; nf < 4; nf++) {
        int col = ccol0 + nf * 16 + (lane & 15);
        float bv = bias[col];
        for (int mf = 0; mf < 4; mf++) {
            int rowb = crow0 + mf * 16 + (lane >> 4) * 4;
            for (int r = 0; r < 4; r++) {
                int row = rowb + r;
                float val = acc[mf][nf][r] + bv;
                if (MODE == 2) {
                    ((float*)outp)[(size_t)row * 1024 + col] = val;
                } else {
                    int b = row >> 11, nq = row & 2047;
                    int h = col >> 6, d = col & 63;
                    unsigned short bfv = f2bf(val);
                    if (MODE == 0)
                        ((unsigned short*)outp)[(((size_t)(b * H_ + h)) * NQ_ + nq) * 64 + d] = bfv;
                    else
                        ((unsigned short*)outp)[(((size_t)(b * H_ + h)) * 64 + d) * NK_ + nq] = bfv;
                }
            }
        }
    }
}

// --------------------------------------------------------- flash attention
// Q,K: [B*H][2048][64] bf16 ; Vt: [B*H][64][2048] bf16
// out attended: [B*NQ][1024] bf16
// 8 waves x 16 q-rows = QBLK 128. Swapped QK^T, in-register softmax,
// defer-max. P via per-wave XOR-swizzled LDS tile [16 q][8 slots x 16B]
// (slot s stored at s^(q&7) -- same conflict-breaking scheme as K/V reads).
__global__ __launch_bounds__(512, 6) void flash_attn(const unsigned short* __restrict__ Q,
                                                     const unsigned short* __restrict__ K,
                                                     const unsigned short* __restrict__ Vt,
                                                     unsigned short* __restrict__ attended) {
    __shared__ __align__(16) char smem[2][16384];        // [buf][ K 8KB | V 8KB ]
    __shared__ __align__(16) unsigned short Ps[8][1024]; // per-wave P tile, 2KB each
    int tid = threadIdx.x, lane = tid & 63, wid = tid >> 6;  // wid 0..7
    int g = lane >> 4;
    int q = lane & 15;

    int bh = blockIdx.y;
    int q0 = blockIdx.x * 128;
    const char* Qb = (const char*)(Q + (size_t)bh * NQ_ * 64);
    const char* Kb = (const char*)(K + (size_t)bh * NK_ * 64);
    const char* Vb = (const char*)(Vt + (size_t)bh * 64 * NK_);

    // Q fragments (B-operand of swapped QK^T), held for the whole kernel
    int qrow = q0 + wid * 16 + q;
    bf16x8 qf[2];
    qf[0] = *(const bf16x8*)(Qb + (size_t)qrow * 128 + g * 16);
    qf[1] = *(const bf16x8*)(Qb + (size_t)qrow * 128 + g * 16 + 64);

    f32x4 acc[4];
    for (int i = 0; i < 4; i++) acc[i] = (f32x4){0.f, 0.f, 0.f, 0.f};
    float mst = -3.0e38f;
    float lst = 0.f;

    // staging: each wave stages 8 K-rows and 8 V-rows per tile (1KB each)
    int sxor = ((lane & 7) * 16) ^ (((lane >> 3) & 7) << 4);
    const char* kptr = Kb + (size_t)(wid * 8 + (lane >> 3)) * 128 + sxor;   // +8192/tile
    const char* vptr = Vb + (size_t)(wid * 8 + (lane >> 3)) * 4096 + sxor;  // +128/tile
    int cb0 = g * 16;
    int swz = (lane & 7) << 4;

    unsigned short* Pw = Ps[wid];
    uint32_t* P32 = (uint32_t*)Pw;
    int pwbase = q * 32 + ((g & 1) << 1);  // u32 index base for P writes
    int q7 = q & 7;

    // prologue stage tile 0
    GLL16(kptr, smem[0] + wid * 1024);
    GLL16(vptr, smem[0] + 8192 + wid * 1024);
    kptr += 8192;
    vptr += 128;
    __syncthreads();
    int cur = 0;

    for (int t = 0; t < NK_ / 64; ++t) {
        if (t < NK_ / 64 - 1) {
            GLL16(kptr, smem[cur ^ 1] + wid * 1024);
            GLL16(vptr, smem[cur ^ 1] + 8192 + wid * 1024);
            kptr += 8192;
            vptr += 128;
        }
        const char* Ksb = smem[cur];
        const char* Vsb = smem[cur] + 8192;

        // S^T = K Q^T : lane holds q-row q, keys {16nf + 4g + r}
        f32x4 s[4];
#pragma unroll
        for (int nf = 0; nf < 4; nf++) {
            s[nf] = (f32x4){0.f, 0.f, 0.f, 0.f};
#pragma unroll
            for (int kk = 0; kk < 2; kk++) {
                bf16x8 kf = *(const bf16x8*)(Ksb + (nf * 16 + q) * 128 + ((cb0 + kk * 64) ^ swz));
                s[nf] = MFMA16(kf, qf[kk], s[nf]);
            }
        }

        // online softmax over the lane's 16 keys + cross-replica reduce
        float mloc = s[0][0];
#pragma unroll
        for (int nf = 0; nf < 4; nf++)
#pragma unroll
            for (int r = 0; r < 4; r++) mloc = fmaxf(mloc, s[nf][r]);
        mloc = fmaxf(mloc, __shfl_xor(mloc, 16));
        mloc = fmaxf(mloc, __shfl_xor(mloc, 32));

        // defer-max: rescale only when max grew enough to matter (P <= 2^8)
        if (!__all(mloc - mst <= 44.36f)) {
            float mnew = fmaxf(mst, mloc);
            float alpha = __builtin_amdgcn_exp2f((mst - mnew) * C2);
            mst = mnew;
            lst *= alpha;
            float al[4];
#pragma unroll
            for (int r = 0; r < 4; r++) al[r] = __shfl(alpha, 4 * g + r);
#pragma unroll
            for (int df = 0; df < 4; df++)
#pragma unroll
                for (int r = 0; r < 4; r++) acc[df][r] *= al[r];
        }

        float mc = mst * C2;
        float p[4][4];
        float psum = 0.f;
#pragma unroll
        for (int nf = 0; nf < 4; nf++)
#pragma unroll
            for (int r = 0; r < 4; r++) {
                float e = __builtin_amdgcn_exp2f(s[nf][r] * C2 - mc);
                p[nf][r] = e;
                psum += e;
            }
        psum += __shfl_xor(psum, 16);
        psum += __shfl_xor(psum, 32);
        lst += psum;

        // write P[q][key] to swizzled per-wave LDS.
        // key k -> slot s=k>>3 stored at position s^(q&7); within-slot ushort k&7.
        // keys this lane holds: 16nf+4g+r  ->  s = 2nf+(g>>1), k&7 = 4(g&1)+r
#pragma unroll
        for (int nf = 0; nf < 4; nf++) {
            int idx = pwbase + (((2 * nf + (g >> 1)) ^ q7) << 2);
            P32[idx]     = packbf2(p[nf][0], p[nf][1]);
            P32[idx + 1] = packbf2(p[nf][2], p[nf][3]);
        }

        // O^acc += P V : A-frag = P[q][keys 8g+32kk .. +7] = slot g+4kk at pos (g+4kk)^(q&7)
#pragma unroll
        for (int kk = 0; kk < 2; kk++) {
            bf16x8 ap = *(const bf16x8*)((const char*)Pw + q * 128 + (((g + 4 * kk) ^ q7) << 4));
#pragma unroll
            for (int df = 0; df < 4; df++) {
                bf16x8 bv = *(const bf16x8*)(Vsb + (df * 16 + q) * 128 + ((cb0 + kk * 64) ^ swz));
                acc[df] = MFMA16(ap, bv, acc[df]);
            }
        }
        __syncthreads();
        cur ^= 1;
    }

    int b = bh >> 4, h = bh & 15;
    float li[4];
#pragma unroll
    for (int r = 0; r < 4; r++) li[r] = 1.0f / __shfl(lst, 4 * g + r);
#pragma unroll
    for (int df = 0; df < 4; df++)
#pragma unroll
        for (int r = 0; r < 4; r++) {
            int row = q0 + wid * 16 + 4 * g + r;
            int col = h * 64 + df * 16 + q;
            attended[(size_t)(b * NQ_ + row) * CQ_ + col] = f2bf(acc[df][r] * li[r]);
        }
}

// ---------------------------------------------------------------- launcher
extern "C" void kernel_launch(void* const* d_in, const int* in_sizes, int n_in,
                              void* d_out, int out_size, void* d_ws, size_t ws_size,
                              hipStream_t stream) {
    const float* qt  = (const float*)d_in[0];
    const float* ct  = (const float*)d_in[1];
    const float* Wq  = (const float*)d_in[2];
    const float* bq  = (const float*)d_in[3];
    const float* Wk  = (const float*)d_in[4];
    const float* bk  = (const float*)d_in[5];
    const float* Wv  = (const float*)d_in[6];
    const float* bv  = (const float*)d_in[7];
    const float* Wo  = (const float*)d_in[8];
    const float* bo  = (const float*)d_in[9];
    const float* gq  = (const float*)d_in[10];
    const float* btq = (const float*)d_in[11];
    const float* gc  = (const float*)d_in[12];
    const float* btc = (const float*)d_in[13];

    char* ws = (char*)d_ws;
    unsigned short* xq  = (unsigned short*)(ws + 0);         // 16 MB (reused as attended)
    unsigned short* xc  = (unsigned short*)(ws + 16777216);  // 12 MB
    unsigned short* Wqt = (unsigned short*)(ws + 29360128);  // 2 MB
    unsigned short* Wkt = (unsigned short*)(ws + 31457280);  // 1.5 MB
    unsigned short* Wvt = (unsigned short*)(ws + 33030144);  // 1.5 MB
    unsigned short* Wot = (unsigned short*)(ws + 34603008);  // 2 MB
    unsigned short* Qb  = (unsigned short*)(ws + 36700160);  // 16 MB
    unsigned short* Kb  = (unsigned short*)(ws + 53477376);  // 16 MB
    unsigned short* Vtb = (unsigned short*)(ws + 70254592);  // 16 MB  (total ~83 MB)

    ln_bf16<1024><<<8192, 256, 0, stream>>>(qt, gq, btq, xq);
    ln_bf16<768><<<8192, 256, 0, stream>>>(ct, gc, btc, xc);

    transpose_cast<<<dim3(32, 32), dim3(32, 8), 0, stream>>>(Wq, Wqt, 1024, 1024);
    transpose_cast<<<dim3(32, 24), dim3(32, 8), 0, stream>>>(Wk, Wkt, 768, 1024);
    transpose_cast<<<dim3(32, 24), dim3(32, 8), 0, stream>>>(Wv, Wvt, 768, 1024);
    transpose_cast<<<dim3(32, 32), dim3(32, 8), 0, stream>>>(Wo, Wot, 1024, 1024);

    gemm_bt<0><<<dim3(8, 64), 256, 0, stream>>>(xq, Wqt, bq, Qb, 1024);
    gemm_bt<0><<<dim3(8, 64), 256, 0, stream>>>(xc, Wkt, bk, Kb, 768);
    gemm_bt<1><<<dim3(8, 64), 256, 0, stream>>>(xc, Wvt, bv, Vtb, 768);

    flash_attn<<<dim3(16, 64), 512, 0, stream>>>(Qb, Kb, Vtb, xq);

    gemm_bt<2><<<dim3(8, 64), 256, 0, stream>>>(xq, Wot, bo, d_out, 1024);
}

// Round 5
// 222.756 us; speedup vs baseline: 1.5425x; 1.0686x over previous
//
#include <hip/hip_runtime.h>
#include <hip/hip_bf16.h>
#include <stdint.h>

#define B_    4
#define NQ_   2048
#define NK_   2048
#define CQ_   1024
#define CK_   768
#define H_    16
#define D_    64
#define SCALE 0.125f   // 1/sqrt(64)
#define C2    0.1803368801111204f  // SCALE * log2(e)

typedef __attribute__((ext_vector_type(8))) short bf16x8;
typedef __attribute__((ext_vector_type(4))) float f32x4;

#define MFMA16(a, b, c) __builtin_amdgcn_mfma_f32_16x16x32_bf16((a), (b), (c), 0, 0, 0)

// async global->LDS, 16B per lane; LDS dest = wave-uniform base + lane*16
#define GLL16(gp, lp)                                                                 \
    __builtin_amdgcn_global_load_lds(                                                 \
        (__attribute__((address_space(1))) uint32_t*)(uintptr_t)(gp),                 \
        (__attribute__((address_space(3))) uint32_t*)(uintptr_t)(lp), 16, 0, 0)

__device__ inline unsigned short f2bf(float f) {
    union { float f; uint32_t u; } v; v.f = f;
    uint32_t u = v.u;
    return (unsigned short)((u + 0x7fffu + ((u >> 16) & 1u)) >> 16);
}

__device__ inline uint32_t packbf2(float a, float b) {
    union { __hip_bfloat162 h; uint32_t u; } v;
    v.h = __float22bfloat162_rn(float2{a, b});
    return v.u;
}

// ---------------------------------------------------------------- LayerNorm
template <int W>
__global__ __launch_bounds__(256) void ln_bf16(const float* __restrict__ x,
                                               const float* __restrict__ gamma,
                                               const float* __restrict__ beta,
                                               unsigned short* __restrict__ out) {
    int row = blockIdx.x;
    int tid = threadIdx.x;
    int col = tid * 4;
    const float* xr = x + (size_t)row * W;
    float v0 = 0.f, v1 = 0.f, v2 = 0.f, v3 = 0.f;
    float s = 0.f, s2 = 0.f;
    bool active = (col < W);
    if (active) {
        float4 vv = *(const float4*)(xr + col);
        v0 = vv.x; v1 = vv.y; v2 = vv.z; v3 = vv.w;
        s = v0 + v1 + v2 + v3;
        s2 = v0 * v0 + v1 * v1 + v2 * v2 + v3 * v3;
    }
    for (int off = 32; off >= 1; off >>= 1) {
        s += __shfl_xor(s, off);
        s2 += __shfl_xor(s2, off);
    }
    __shared__ float red[8];
    __shared__ float stat[2];
    int wid = tid >> 6, lane = tid & 63;
    if (lane == 0) { red[wid] = s; red[4 + wid] = s2; }
    __syncthreads();
    if (tid == 0) {
        float ts = red[0] + red[1] + red[2] + red[3];
        float ts2 = red[4] + red[5] + red[6] + red[7];
        float mu = ts / (float)W;
        float var = ts2 / (float)W - mu * mu;
        stat[0] = mu;
        stat[1] = rsqrtf(var + 1e-5f);
    }
    __syncthreads();
    float mu = stat[0], rstd = stat[1];
    if (active) {
        float4 g = *(const float4*)(gamma + col);
        float4 b = *(const float4*)(beta + col);
        ushort4 o;
        o.x = f2bf((v0 - mu) * rstd * g.x + b.x);
        o.y = f2bf((v1 - mu) * rstd * g.y + b.y);
        o.z = f2bf((v2 - mu) * rstd * g.z + b.z);
        o.w = f2bf((v3 - mu) * rstd * g.w + b.w);
        *(ushort4*)(out + (size_t)row * W + col) = o;
    }
}

// -------------------------------------------------- weight transpose + cast
__global__ __launch_bounds__(256) void transpose_cast(const float* __restrict__ Wsrc,
                                                      unsigned short* __restrict__ Wt,
                                                      int K, int N) {
    __shared__ float t[32][33];
    int n0 = blockIdx.x * 32, k0 = blockIdx.y * 32;
    int tx = threadIdx.x, ty = threadIdx.y;  // 32 x 8
    for (int i = 0; i < 4; i++)
        t[ty + 8 * i][tx] = Wsrc[(size_t)(k0 + ty + 8 * i) * N + n0 + tx];
    __syncthreads();
    for (int i = 0; i < 4; i++)
        Wt[(size_t)(n0 + ty + 8 * i) * K + k0 + tx] = f2bf(t[tx][ty + 8 * i]);
}

// ------------------------------------------------------------------- GEMM
// Y[M=8192][1024] = X[M][Kd] @ Wt[1024][Kd]^T + bias
// MODE 0: bf16 out remapped [b][h][n][64]   (Q / K)
// MODE 1: bf16 out remapped [b][h][64][nk]  (V transposed)
// MODE 2: fp32 out plain [M][1024]          (final O)
// Grid is 512 blocks; chunked XCD swizzle so each XCD's 64 blocks form an
// 8m x 8n region (A-panels 2MB + B 2MB ~= one XCD L2).
template <int MODE>
__global__ __launch_bounds__(256) void gemm_bt(const unsigned short* __restrict__ X,
                                               const unsigned short* __restrict__ Wt,
                                               const float* __restrict__ bias,
                                               void* __restrict__ outp, int Kd) {
    __shared__ __align__(16) unsigned short As[128 * 64];
    __shared__ __align__(16) unsigned short Bs[128 * 64];
    int tid = threadIdx.x;
    int lane = tid & 63, wid = tid >> 6;

    int lin = blockIdx.y * 8 + blockIdx.x;       // 0..511
    int virt = (lin & 7) * 64 + (lin >> 3);      // bijective chunked map
    int m0 = (virt >> 3) * 128;
    int n0 = (virt & 7) * 128;
    int wm = wid >> 1, wn = wid & 1;

    f32x4 acc[4][4];
    for (int i = 0; i < 4; i++)
        for (int j = 0; j < 4; j++) acc[i][j] = (f32x4){0.f, 0.f, 0.f, 0.f};

    int srow = wid * 8 + (lane >> 3);
    int sxor = ((lane & 7) * 16) ^ (((lane >> 3) & 7) << 4);
    int swz = (lane & 7) << 4;
    const char* Xb = (const char*)X;
    const char* Wb = (const char*)Wt;
    char* AsB = (char*)As;
    char* BsB = (char*)Bs;

    for (int k0 = 0; k0 < Kd; k0 += 64) {
        for (int i = 0; i < 4; i++) {
            int row = i * 32 + srow;
            GLL16(Xb + ((size_t)(m0 + row) * Kd + k0) * 2 + sxor, AsB + i * 4096 + wid * 1024);
            GLL16(Wb + ((size_t)(n0 + row) * Kd + k0) * 2 + sxor, BsB + i * 4096 + wid * 1024);
        }
        __syncthreads();
        for (int kk = 0; kk < 2; kk++) {
            int cb = (((lane >> 4) * 16 + kk * 64) ^ swz);
            bf16x8 a[4], b[4];
            for (int mf = 0; mf < 4; mf++)
                a[mf] = *(const bf16x8*)(AsB + (wm * 64 + mf * 16 + (lane & 15)) * 128 + cb);
            for (int nf = 0; nf < 4; nf++)
                b[nf] = *(const bf16x8*)(BsB + (wn * 64 + nf * 16 + (lane & 15)) * 128 + cb);
            for (int mf = 0; mf < 4; mf++)
                for (int nf = 0; nf < 4; nf++) acc[mf][nf] = MFMA16(a[mf], b[nf], acc[mf][nf]);
        }
        __syncthreads();
    }

    int crow0 = m0 + wm * 64;
    int ccol0 = n0 + wn * 64;
    for (int nf = 0; nf < 4; nf++) {
        int col = ccol0 + nf * 16 + (lane & 15);
        float bv = bias[col];
        for (int mf = 0; mf < 4; mf++) {
            int rowb = crow0 + mf * 16 + (lane >> 4) * 4;
            for (int r = 0; r < 4; r++) {
                int row = rowb + r;
                float val = acc[mf][nf][r] + bv;
                if (MODE == 2) {
                    ((float*)outp)[(size_t)row * 1024 + col] = val;
                } else {
                    int b = row >> 11, nq = row & 2047;
                    int h = col >> 6, d = col & 63;
                    unsigned short bfv = f2bf(val);
                    if (MODE == 0)
                        ((unsigned short*)outp)[(((size_t)(b * H_ + h)) * NQ_ + nq) * 64 + d] = bfv;
                    else
                        ((unsigned short*)outp)[(((size_t)(b * H_ + h)) * 64 + d) * NK_ + nq] = bfv;
                }
            }
        }
    }
}

// --------------------------------------------------------- flash attention
// Q,K: [B*H][2048][64] bf16 ; Vt: [B*H][64][2048] bf16
// out attended: [B*NQ][1024] bf16
// 8 waves x 16 q-rows = QBLK 128. Swapped QK^T, in-register softmax,
// defer-max, P via per-wave XOR-swizzled LDS tile. Row-sum l computed by an
// extra ones-column MFMA in the PV step (no VALU reduce, no end shuffles).
// Chunked XCD swizzle: each XCD's 128 blocks cover 8 bh (K+V 4MB -> L2-fit).
__global__ __launch_bounds__(512, 6) void flash_attn(const unsigned short* __restrict__ Q,
                                                     const unsigned short* __restrict__ K,
                                                     const unsigned short* __restrict__ Vt,
                                                     unsigned short* __restrict__ attended) {
    __shared__ __align__(16) char smem[2][16384];        // [buf][ K 8KB | V 8KB ]
    __shared__ __align__(16) unsigned short Ps[8][1024]; // per-wave P tile, 2KB each
    int tid = threadIdx.x, lane = tid & 63, wid = tid >> 6;  // wid 0..7
    int g = lane >> 4;
    int q = lane & 15;

    int lin = blockIdx.y * 16 + blockIdx.x;      // 0..1023
    int virt = (lin & 7) * 128 + (lin >> 3);     // bijective chunked map
    int bh = virt >> 4;
    int q0 = (virt & 15) * 128;
    const char* Qb = (const char*)(Q + (size_t)bh * NQ_ * 64);
    const char* Kb = (const char*)(K + (size_t)bh * NK_ * 64);
    const char* Vb = (const char*)(Vt + (size_t)bh * 64 * NK_);

    // Q fragments (B-operand of swapped QK^T), held for the whole kernel
    int qrow = q0 + wid * 16 + q;
    bf16x8 qf[2];
    qf[0] = *(const bf16x8*)(Qb + (size_t)qrow * 128 + g * 16);
    qf[1] = *(const bf16x8*)(Qb + (size_t)qrow * 128 + g * 16 + 64);

    bf16x8 onesf;
#pragma unroll
    for (int i = 0; i < 8; i++) onesf[i] = (short)0x3f80;  // bf16 1.0

    f32x4 acc[4];
    for (int i = 0; i < 4; i++) acc[i] = (f32x4){0.f, 0.f, 0.f, 0.f};
    f32x4 accl = (f32x4){0.f, 0.f, 0.f, 0.f};  // row-sums l via ones-MFMA
    float mst = -3.0e38f;

    // staging: each wave stages 8 K-rows and 8 V-rows per tile (1KB each)
    int sxor = ((lane & 7) * 16) ^ (((lane >> 3) & 7) << 4);
    const char* kptr = Kb + (size_t)(wid * 8 + (lane >> 3)) * 128 + sxor;   // +8192/tile
    const char* vptr = Vb + (size_t)(wid * 8 + (lane >> 3)) * 4096 + sxor;  // +128/tile
    int cb0 = g * 16;
    int swz = (lane & 7) << 4;

    unsigned short* Pw = Ps[wid];
    uint32_t* P32 = (uint32_t*)Pw;
    int pwbase = q * 32 + ((g & 1) << 1);  // u32 index base for P writes
    int q7 = q & 7;

    // prologue stage tile 0
    GLL16(kptr, smem[0] + wid * 1024);
    GLL16(vptr, smem[0] + 8192 + wid * 1024);
    kptr += 8192;
    vptr += 128;
    __syncthreads();
    int cur = 0;

    for (int t = 0; t < NK_ / 64; ++t) {
        if (t < NK_ / 64 - 1) {
            GLL16(kptr, smem[cur ^ 1] + wid * 1024);
            GLL16(vptr, smem[cur ^ 1] + 8192 + wid * 1024);
            kptr += 8192;
            vptr += 128;
        }
        const char* Ksb = smem[cur];
        const char* Vsb = smem[cur] + 8192;

        // S^T = K Q^T : lane holds q-row q, keys {16nf + 4g + r}
        f32x4 s[4];
        __builtin_amdgcn_s_setprio(1);
#pragma unroll
        for (int nf = 0; nf < 4; nf++) {
            s[nf] = (f32x4){0.f, 0.f, 0.f, 0.f};
#pragma unroll
            for (int kk = 0; kk < 2; kk++) {
                bf16x8 kf = *(const bf16x8*)(Ksb + (nf * 16 + q) * 128 + ((cb0 + kk * 64) ^ swz));
                s[nf] = MFMA16(kf, qf[kk], s[nf]);
            }
        }
        __builtin_amdgcn_s_setprio(0);

        // local max over lane's 16 keys (max3-fusable triples) + 2 shuffles
        float ma = fmaxf(fmaxf(s[0][0], s[0][1]), s[0][2]);
        float mb = fmaxf(fmaxf(s[0][3], s[1][0]), s[1][1]);
        float mcx = fmaxf(fmaxf(s[1][2], s[1][3]), s[2][0]);
        float md = fmaxf(fmaxf(s[2][1], s[2][2]), s[2][3]);
        float me = fmaxf(fmaxf(s[3][0], s[3][1]), s[3][2]);
        float mloc = fmaxf(fmaxf(fmaxf(ma, mb), fmaxf(mcx, md)), fmaxf(me, s[3][3]));
        mloc = fmaxf(mloc, __shfl_xor(mloc, 16));
        mloc = fmaxf(mloc, __shfl_xor(mloc, 32));

        // defer-max: rescale only when max grew enough to matter (P <= 2^8)
        if (!__all(mloc - mst <= 44.36f)) {
            float mnew = fmaxf(mst, mloc);
            float alpha = __builtin_amdgcn_exp2f((mst - mnew) * C2);
            mst = mnew;
            float al[4];
#pragma unroll
            for (int r = 0; r < 4; r++) al[r] = __shfl(alpha, 4 * g + r);
#pragma unroll
            for (int r = 0; r < 4; r++) {
#pragma unroll
                for (int df = 0; df < 4; df++) acc[df][r] *= al[r];
                accl[r] *= al[r];
            }
        }

        float mc = mst * C2;
        float p[4][4];
#pragma unroll
        for (int nf = 0; nf < 4; nf++)
#pragma unroll
            for (int r = 0; r < 4; r++)
                p[nf][r] = __builtin_amdgcn_exp2f(s[nf][r] * C2 - mc);

        // write P[q][key] to swizzled per-wave LDS.
        // key k -> slot s=k>>3 stored at position s^(q&7); within-slot ushort k&7.
        // keys this lane holds: 16nf+4g+r  ->  s = 2nf+(g>>1), k&7 = 4(g&1)+r
#pragma unroll
        for (int nf = 0; nf < 4; nf++) {
            int idx = pwbase + (((2 * nf + (g >> 1)) ^ q7) << 2);
            P32[idx]     = packbf2(p[nf][0], p[nf][1]);
            P32[idx + 1] = packbf2(p[nf][2], p[nf][3]);
        }

        // O^acc += P V ; l^acc += P 1  (ones-column MFMA replaces VALU reduce)
        __builtin_amdgcn_s_setprio(1);
#pragma unroll
        for (int kk = 0; kk < 2; kk++) {
            bf16x8 ap = *(const bf16x8*)((const char*)Pw + q * 128 + (((g + 4 * kk) ^ q7) << 4));
            accl = MFMA16(ap, onesf, accl);
#pragma unroll
            for (int df = 0; df < 4; df++) {
                bf16x8 bv = *(const bf16x8*)(Vsb + (df * 16 + q) * 128 + ((cb0 + kk * 64) ^ swz));
                acc[df] = MFMA16(ap, bv, acc[df]);
            }
        }
        __builtin_amdgcn_s_setprio(0);
        __syncthreads();
        cur ^= 1;
    }

    int b = bh >> 4, h = bh & 15;
#pragma unroll
    for (int df = 0; df < 4; df++)
#pragma unroll
        for (int r = 0; r < 4; r++) {
            int row = q0 + wid * 16 + 4 * g + r;
            int col = h * 64 + df * 16 + q;
            attended[(size_t)(b * NQ_ + row) * CQ_ + col] = f2bf(acc[df][r] / accl[r]);
        }
}

// ---------------------------------------------------------------- launcher
extern "C" void kernel_launch(void* const* d_in, const int* in_sizes, int n_in,
                              void* d_out, int out_size, void* d_ws, size_t ws_size,
                              hipStream_t stream) {
    const float* qt  = (const float*)d_in[0];
    const float* ct  = (const float*)d_in[1];
    const float* Wq  = (const float*)d_in[2];
    const float* bq  = (const float*)d_in[3];
    const float* Wk  = (const float*)d_in[4];
    const float* bk  = (const float*)d_in[5];
    const float* Wv  = (const float*)d_in[6];
    const float* bv  = (const float*)d_in[7];
    const float* Wo  = (const float*)d_in[8];
    const float* bo  = (const float*)d_in[9];
    const float* gq  = (const float*)d_in[10];
    const float* btq = (const float*)d_in[11];
    const float* gc  = (const float*)d_in[12];
    const float* btc = (const float*)d_in[13];

    char* ws = (char*)d_ws;
    unsigned short* xq  = (unsigned short*)(ws + 0);         // 16 MB (reused as attended)
    unsigned short* xc  = (unsigned short*)(ws + 16777216);  // 12 MB
    unsigned short* Wqt = (unsigned short*)(ws + 29360128);  // 2 MB
    unsigned short* Wkt = (unsigned short*)(ws + 31457280);  // 1.5 MB
    unsigned short* Wvt = (unsigned short*)(ws + 33030144);  // 1.5 MB
    unsigned short* Wot = (unsigned short*)(ws + 34603008);  // 2 MB
    unsigned short* Qb  = (unsigned short*)(ws + 36700160);  // 16 MB
    unsigned short* Kb  = (unsigned short*)(ws + 53477376);  // 16 MB
    unsigned short* Vtb = (unsigned short*)(ws + 70254592);  // 16 MB  (total ~83 MB)

    ln_bf16<1024><<<8192, 256, 0, stream>>>(qt, gq, btq, xq);
    ln_bf16<768><<<8192, 256, 0, stream>>>(ct, gc, btc, xc);

    transpose_cast<<<dim3(32, 32), dim3(32, 8), 0, stream>>>(Wq, Wqt, 1024, 1024);
    transpose_cast<<<dim3(32, 24), dim3(32, 8), 0, stream>>>(Wk, Wkt, 768, 1024);
    transpose_cast<<<dim3(32, 24), dim3(32, 8), 0, stream>>>(Wv, Wvt, 768, 1024);
    transpose_cast<<<dim3(32, 32), dim3(32, 8), 0, stream>>>(Wo, Wot, 1024, 1024);

    gemm_bt<0><<<dim3(8, 64), 256, 0, stream>>>(xq, Wqt, bq, Qb, 1024);
    gemm_bt<0><<<dim3(8, 64), 256, 0, stream>>>(xc, Wkt, bk, Kb, 768);
    gemm_bt<1><<<dim3(8, 64), 256, 0, stream>>>(xc, Wvt, bv, Vtb, 768);

    flash_attn<<<dim3(16, 64), 512, 0, stream>>>(Qb, Kb, Vtb, xq);

    gemm_bt<2><<<dim3(8, 64), 256, 0, stream>>>(xq, Wot, bo, d_out, 1024);
}

// Round 6
// 209.855 us; speedup vs baseline: 1.6374x; 1.0615x over previous
//
#include <hip/hip_runtime.h>
#include <hip/hip_bf16.h>
#include <stdint.h>

#define B_    4
#define NQ_   2048
#define NK_   2048
#define CQ_   1024
#define CK_   768
#define H_    16
#define D_    64
#define SCALE 0.125f   // 1/sqrt(64)
#define C2    0.1803368801111204f  // SCALE * log2(e)

typedef __attribute__((ext_vector_type(8))) short bf16x8;
typedef __attribute__((ext_vector_type(4))) float f32x4;

#define MFMA16(a, b, c) __builtin_amdgcn_mfma_f32_16x16x32_bf16((a), (b), (c), 0, 0, 0)

// async global->LDS, 16B per lane; LDS dest = wave-uniform base + lane*16
#define GLL16(gp, lp)                                                                 \
    __builtin_amdgcn_global_load_lds(                                                 \
        (__attribute__((address_space(1))) uint32_t*)(uintptr_t)(gp),                 \
        (__attribute__((address_space(3))) uint32_t*)(uintptr_t)(lp), 16, 0, 0)

__device__ inline unsigned short f2bf(float f) {
    union { float f; uint32_t u; } v; v.f = f;
    uint32_t u = v.u;
    return (unsigned short)((u + 0x7fffu + ((u >> 16) & 1u)) >> 16);
}

__device__ inline uint32_t packbf2(float a, float b) {
    union { __hip_bfloat162 h; uint32_t u; } v;
    v.h = __float22bfloat162_rn(float2{a, b});
    return v.u;
}

// ---------------------------------------------------------------- LayerNorm
template <int W>
__global__ __launch_bounds__(256) void ln_bf16(const float* __restrict__ x,
                                               const float* __restrict__ gamma,
                                               const float* __restrict__ beta,
                                               unsigned short* __restrict__ out) {
    int row = blockIdx.x;
    int tid = threadIdx.x;
    int col = tid * 4;
    const float* xr = x + (size_t)row * W;
    float v0 = 0.f, v1 = 0.f, v2 = 0.f, v3 = 0.f;
    float s = 0.f, s2 = 0.f;
    bool active = (col < W);
    if (active) {
        float4 vv = *(const float4*)(xr + col);
        v0 = vv.x; v1 = vv.y; v2 = vv.z; v3 = vv.w;
        s = v0 + v1 + v2 + v3;
        s2 = v0 * v0 + v1 * v1 + v2 * v2 + v3 * v3;
    }
    for (int off = 32; off >= 1; off >>= 1) {
        s += __shfl_xor(s, off);
        s2 += __shfl_xor(s2, off);
    }
    __shared__ float red[8];
    __shared__ float stat[2];
    int wid = tid >> 6, lane = tid & 63;
    if (lane == 0) { red[wid] = s; red[4 + wid] = s2; }
    __syncthreads();
    if (tid == 0) {
        float ts = red[0] + red[1] + red[2] + red[3];
        float ts2 = red[4] + red[5] + red[6] + red[7];
        float mu = ts / (float)W;
        float var = ts2 / (float)W - mu * mu;
        stat[0] = mu;
        stat[1] = rsqrtf(var + 1e-5f);
    }
    __syncthreads();
    float mu = stat[0], rstd = stat[1];
    if (active) {
        float4 g = *(const float4*)(gamma + col);
        float4 b = *(const float4*)(beta + col);
        ushort4 o;
        o.x = f2bf((v0 - mu) * rstd * g.x + b.x);
        o.y = f2bf((v1 - mu) * rstd * g.y + b.y);
        o.z = f2bf((v2 - mu) * rstd * g.z + b.z);
        o.w = f2bf((v3 - mu) * rstd * g.w + b.w);
        *(ushort4*)(out + (size_t)row * W + col) = o;
    }
}

// -------------------------------------------------- weight transpose + cast
__global__ __launch_bounds__(256) void transpose_cast(const float* __restrict__ Wsrc,
                                                      unsigned short* __restrict__ Wt,
                                                      int K, int N) {
    __shared__ float t[32][33];
    int n0 = blockIdx.x * 32, k0 = blockIdx.y * 32;
    int tx = threadIdx.x, ty = threadIdx.y;  // 32 x 8
    for (int i = 0; i < 4; i++)
        t[ty + 8 * i][tx] = Wsrc[(size_t)(k0 + ty + 8 * i) * N + n0 + tx];
    __syncthreads();
    for (int i = 0; i < 4; i++)
        Wt[(size_t)(n0 + ty + 8 * i) * K + k0 + tx] = f2bf(t[tx][ty + 8 * i]);
}

// ------------------------------------------------------------------- GEMM
// Y[M=8192][1024] = X[M][Kd] @ Wt[1024][Kd]^T + bias
// MODE 0: bf16 out remapped [b][h][n][64]   (Q / K)
// MODE 1: bf16 out remapped [b][h][64][nk]  (V transposed)
// MODE 2: fp32 out plain [M][1024]          (final O)
// Grid is 512 blocks; chunked XCD swizzle so each XCD's 64 blocks form an
// 8m x 8n region (A-panels 2MB + B 2MB ~= one XCD L2).
template <int MODE>
__global__ __launch_bounds__(256) void gemm_bt(const unsigned short* __restrict__ X,
                                               const unsigned short* __restrict__ Wt,
                                               const float* __restrict__ bias,
                                               void* __restrict__ outp, int Kd) {
    __shared__ __align__(16) unsigned short As[128 * 64];
    __shared__ __align__(16) unsigned short Bs[128 * 64];
    int tid = threadIdx.x;
    int lane = tid & 63, wid = tid >> 6;

    int lin = blockIdx.y * 8 + blockIdx.x;       // 0..511
    int virt = (lin & 7) * 64 + (lin >> 3);      // bijective chunked map
    int m0 = (virt >> 3) * 128;
    int n0 = (virt & 7) * 128;
    int wm = wid >> 1, wn = wid & 1;

    f32x4 acc[4][4];
    for (int i = 0; i < 4; i++)
        for (int j = 0; j < 4; j++) acc[i][j] = (f32x4){0.f, 0.f, 0.f, 0.f};

    int srow = wid * 8 + (lane >> 3);
    int sxor = ((lane & 7) * 16) ^ (((lane >> 3) & 7) << 4);
    int swz = (lane & 7) << 4;
    const char* Xb = (const char*)X;
    const char* Wb = (const char*)Wt;
    char* AsB = (char*)As;
    char* BsB = (char*)Bs;

    for (int k0 = 0; k0 < Kd; k0 += 64) {
        for (int i = 0; i < 4; i++) {
            int row = i * 32 + srow;
            GLL16(Xb + ((size_t)(m0 + row) * Kd + k0) * 2 + sxor, AsB + i * 4096 + wid * 1024);
            GLL16(Wb + ((size_t)(n0 + row) * Kd + k0) * 2 + sxor, BsB + i * 4096 + wid * 1024);
        }
        __syncthreads();
        for (int kk = 0; kk < 2; kk++) {
            int cb = (((lane >> 4) * 16 + kk * 64) ^ swz);
            bf16x8 a[4], b[4];
            for (int mf = 0; mf < 4; mf++)
                a[mf] = *(const bf16x8*)(AsB + (wm * 64 + mf * 16 + (lane & 15)) * 128 + cb);
            for (int nf = 0; nf < 4; nf++)
                b[nf] = *(const bf16x8*)(BsB + (wn * 64 + nf * 16 + (lane & 15)) * 128 + cb);
            for (int mf = 0; mf < 4; mf++)
                for (int nf = 0; nf < 4; nf++) acc[mf][nf] = MFMA16(a[mf], b[nf], acc[mf][nf]);
        }
        __syncthreads();
    }

    int crow0 = m0 + wm * 64;
    int ccol0 = n0 + wn * 64;
    for (int nf = 0; nf < 4; nf++) {
        int col = ccol0 + nf * 16 + (lane & 15);
        float bv = bias[col];
        for (int mf = 0; mf < 4; mf++) {
            int rowb = crow0 + mf * 16 + (lane >> 4) * 4;
            for (int r = 0; r < 4; r++) {
                int row = rowb + r;
                float val = acc[mf][nf][r] + bv;
                if (MODE == 2) {
                    ((float*)outp)[(size_t)row * 1024 + col] = val;
                } else {
                    int b = row >> 11, nq = row & 2047;
                    int h = col >> 6, d = col & 63;
                    unsigned short bfv = f2bf(val);
                    if (MODE == 0)
                        ((unsigned short*)outp)[(((size_t)(b * H_ + h)) * NQ_ + nq) * 64 + d] = bfv;
                    else
                        ((unsigned short*)outp)[(((size_t)(b * H_ + h)) * 64 + d) * NK_ + nq] = bfv;
                }
            }
        }
    }
}

// --------------------------------------------------------- flash attention
// Q,K: [B*H][2048][64] bf16 ; Vt: [B*H][64][2048] bf16
// out attended: [B*NQ][1024] bf16
// 8 waves x 32 q-rows (2 groups of 16) = QBLK 256. K/V fragments are read
// from LDS ONCE per wave and reused for both q-groups' MFMAs (halves the
// dominant LDS-pipe cost). Shared union max + defer-max across groups.
// Row-sum l via ones-column MFMA. Per-wave P tile 4KB (2KB per group),
// XOR-swizzled, round-1-verified write->read pattern.
__global__ __launch_bounds__(512, 4) void flash_attn(const unsigned short* __restrict__ Q,
                                                     const unsigned short* __restrict__ K,
                                                     const unsigned short* __restrict__ Vt,
                                                     unsigned short* __restrict__ attended) {
    __shared__ __align__(16) char smem[2][16384];        // [buf][ K 8KB | V 8KB ]
    __shared__ __align__(16) unsigned short Ps[8][2048]; // per-wave P, 4KB (2KB/group)
    int tid = threadIdx.x, lane = tid & 63, wid = tid >> 6;  // wid 0..7
    int g = lane >> 4;
    int q = lane & 15;

    int lin = blockIdx.y * 8 + blockIdx.x;       // 0..511
    int virt = (lin & 7) * 64 + (lin >> 3);      // bijective chunked map: 8 bh per XCD
    int bh = virt >> 3;
    int q0 = (virt & 7) * 256;
    const char* Qb = (const char*)(Q + (size_t)bh * NQ_ * 64);
    const char* Kb = (const char*)(K + (size_t)bh * NK_ * 64);
    const char* Vb = (const char*)(Vt + (size_t)bh * 64 * NK_);

    // Q fragments for both groups (B-operand of swapped QK^T)
    int qrow = q0 + wid * 32 + q;
    bf16x8 qf0[2], qf1[2];
    qf0[0] = *(const bf16x8*)(Qb + (size_t)qrow * 128 + g * 16);
    qf0[1] = *(const bf16x8*)(Qb + (size_t)qrow * 128 + g * 16 + 64);
    qf1[0] = *(const bf16x8*)(Qb + (size_t)(qrow + 16) * 128 + g * 16);
    qf1[1] = *(const bf16x8*)(Qb + (size_t)(qrow + 16) * 128 + g * 16 + 64);

    bf16x8 onesf;
#pragma unroll
    for (int i = 0; i < 8; i++) onesf[i] = (short)0x3f80;  // bf16 1.0

    f32x4 acc0[4], acc1[4];
    for (int i = 0; i < 4; i++) {
        acc0[i] = (f32x4){0.f, 0.f, 0.f, 0.f};
        acc1[i] = (f32x4){0.f, 0.f, 0.f, 0.f};
    }
    f32x4 accl0 = (f32x4){0.f, 0.f, 0.f, 0.f};
    f32x4 accl1 = (f32x4){0.f, 0.f, 0.f, 0.f};
    float mst = -3.0e38f;  // shared (union) running max across both groups

    // staging: each wave stages 8 K-rows and 8 V-rows per tile (1KB each)
    int sxor = ((lane & 7) * 16) ^ (((lane >> 3) & 7) << 4);
    const char* kptr = Kb + (size_t)(wid * 8 + (lane >> 3)) * 128 + sxor;   // +8192/tile
    const char* vptr = Vb + (size_t)(wid * 8 + (lane >> 3)) * 4096 + sxor;  // +128/tile
    int cb0 = g * 16;
    int swz = (lane & 7) << 4;

    unsigned short* Pw = Ps[wid];
    uint32_t* P32 = (uint32_t*)Pw;
    int pwbase = q * 32 + ((g & 1) << 1);  // u32 index base for P writes
    int q7 = q & 7;

    // prologue stage tile 0
    GLL16(kptr, smem[0] + wid * 1024);
    GLL16(vptr, smem[0] + 8192 + wid * 1024);
    kptr += 8192;
    vptr += 128;
    __syncthreads();
    int cur = 0;

    for (int t = 0; t < NK_ / 64; ++t) {
        if (t < NK_ / 64 - 1) {
            GLL16(kptr, smem[cur ^ 1] + wid * 1024);
            GLL16(vptr, smem[cur ^ 1] + 8192 + wid * 1024);
            kptr += 8192;
            vptr += 128;
        }
        const char* Ksb = smem[cur];
        const char* Vsb = smem[cur] + 8192;

        // S^T = K Q^T for both groups; kf read once, used twice
        f32x4 s0[4], s1[4];
        __builtin_amdgcn_s_setprio(1);
#pragma unroll
        for (int nf = 0; nf < 4; nf++) {
            s0[nf] = (f32x4){0.f, 0.f, 0.f, 0.f};
            s1[nf] = (f32x4){0.f, 0.f, 0.f, 0.f};
#pragma unroll
            for (int kk = 0; kk < 2; kk++) {
                bf16x8 kf = *(const bf16x8*)(Ksb + (nf * 16 + q) * 128 + ((cb0 + kk * 64) ^ swz));
                s0[nf] = MFMA16(kf, qf0[kk], s0[nf]);
                s1[nf] = MFMA16(kf, qf1[kk], s1[nf]);
            }
        }
        __builtin_amdgcn_s_setprio(0);

        // union max over both groups' 16 keys (tree) + 2 cross-replica shuffles
#define VMAX4(a, b) (f32x4){fmaxf(a[0], b[0]), fmaxf(a[1], b[1]), fmaxf(a[2], b[2]), fmaxf(a[3], b[3])}
        f32x4 x0 = VMAX4(s0[0], s1[0]);
        f32x4 x1 = VMAX4(s0[1], s1[1]);
        f32x4 x2 = VMAX4(s0[2], s1[2]);
        f32x4 x3 = VMAX4(s0[3], s1[3]);
        x0 = VMAX4(x0, x2);
        x1 = VMAX4(x1, x3);
        x0 = VMAX4(x0, x1);
        float mloc = fmaxf(fmaxf(x0[0], x0[1]), fmaxf(x0[2], x0[3]));
        mloc = fmaxf(mloc, __shfl_xor(mloc, 16));
        mloc = fmaxf(mloc, __shfl_xor(mloc, 32));

        // defer-max: rescale only when max grew enough to matter (P <= 2^8)
        if (!__all(mloc - mst <= 44.36f)) {
            float mnew = fmaxf(mst, mloc);
            float alpha = __builtin_amdgcn_exp2f((mst - mnew) * C2);
            mst = mnew;
            float al[4];
#pragma unroll
            for (int r = 0; r < 4; r++) al[r] = __shfl(alpha, 4 * g + r);
#pragma unroll
            for (int r = 0; r < 4; r++) {
#pragma unroll
                for (int df = 0; df < 4; df++) {
                    acc0[df][r] *= al[r];
                    acc1[df][r] *= al[r];
                }
                accl0[r] *= al[r];
                accl1[r] *= al[r];
            }
        }

        float mc = mst * C2;
        // exp + pack + P-write per group. key k -> slot s=k>>3 at pos s^(q&7);
        // keys this lane holds: 16nf+4g+r -> s = 2nf+(g>>1), within-slot 4(g&1)+r
#pragma unroll
        for (int nf = 0; nf < 4; nf++) {
            int idx = pwbase + (((2 * nf + (g >> 1)) ^ q7) << 2);
            {
                float e0 = __builtin_amdgcn_exp2f(s0[nf][0] * C2 - mc);
                float e1 = __builtin_amdgcn_exp2f(s0[nf][1] * C2 - mc);
                float e2 = __builtin_amdgcn_exp2f(s0[nf][2] * C2 - mc);
                float e3 = __builtin_amdgcn_exp2f(s0[nf][3] * C2 - mc);
                P32[idx] = packbf2(e0, e1);
                P32[idx + 1] = packbf2(e2, e3);
            }
            {
                float e0 = __builtin_amdgcn_exp2f(s1[nf][0] * C2 - mc);
                float e1 = __builtin_amdgcn_exp2f(s1[nf][1] * C2 - mc);
                float e2 = __builtin_amdgcn_exp2f(s1[nf][2] * C2 - mc);
                float e3 = __builtin_amdgcn_exp2f(s1[nf][3] * C2 - mc);
                P32[idx + 512] = packbf2(e0, e1);
                P32[idx + 513] = packbf2(e2, e3);
            }
        }

        // O^acc += P V ; l^acc += P 1. bv read once, used by both groups.
        __builtin_amdgcn_s_setprio(1);
#pragma unroll
        for (int kk = 0; kk < 2; kk++) {
            int pb = q * 128 + (((g + 4 * kk) ^ q7) << 4);
            bf16x8 ap0 = *(const bf16x8*)((const char*)Pw + pb);
            bf16x8 ap1 = *(const bf16x8*)((const char*)Pw + 2048 + pb);
            accl0 = MFMA16(ap0, onesf, accl0);
            accl1 = MFMA16(ap1, onesf, accl1);
#pragma unroll
            for (int df = 0; df < 4; df++) {
                bf16x8 bv = *(const bf16x8*)(Vsb + (df * 16 + q) * 128 + ((cb0 + kk * 64) ^ swz));
                acc0[df] = MFMA16(ap0, bv, acc0[df]);
                acc1[df] = MFMA16(ap1, bv, acc1[df]);
            }
        }
        __builtin_amdgcn_s_setprio(0);
        __syncthreads();
        cur ^= 1;
    }

    int b = bh >> 4, h = bh & 15;
#pragma unroll
    for (int df = 0; df < 4; df++)
#pragma unroll
        for (int r = 0; r < 4; r++) {
            int row = q0 + wid * 32 + 4 * g + r;
            int col = h * 64 + df * 16 + q;
            attended[(size_t)(b * NQ_ + row) * CQ_ + col] = f2bf(acc0[df][r] / accl0[r]);
            attended[(size_t)(b * NQ_ + row + 16) * CQ_ + col] = f2bf(acc1[df][r] / accl1[r]);
        }
}

// ---------------------------------------------------------------- launcher
extern "C" void kernel_launch(void* const* d_in, const int* in_sizes, int n_in,
                              void* d_out, int out_size, void* d_ws, size_t ws_size,
                              hipStream_t stream) {
    const float* qt  = (const float*)d_in[0];
    const float* ct  = (const float*)d_in[1];
    const float* Wq  = (const float*)d_in[2];
    const float* bq  = (const float*)d_in[3];
    const float* Wk  = (const float*)d_in[4];
    const float* bk  = (const float*)d_in[5];
    const float* Wv  = (const float*)d_in[6];
    const float* bv  = (const float*)d_in[7];
    const float* Wo  = (const float*)d_in[8];
    const float* bo  = (const float*)d_in[9];
    const float* gq  = (const float*)d_in[10];
    const float* btq = (const float*)d_in[11];
    const float* gc  = (const float*)d_in[12];
    const float* btc = (const float*)d_in[13];

    char* ws = (char*)d_ws;
    unsigned short* xq  = (unsigned short*)(ws + 0);         // 16 MB (reused as attended)
    unsigned short* xc  = (unsigned short*)(ws + 16777216);  // 12 MB
    unsigned short* Wqt = (unsigned short*)(ws + 29360128);  // 2 MB
    unsigned short* Wkt = (unsigned short*)(ws + 31457280);  // 1.5 MB
    unsigned short* Wvt = (unsigned short*)(ws + 33030144);  // 1.5 MB
    unsigned short* Wot = (unsigned short*)(ws + 34603008);  // 2 MB
    unsigned short* Qb  = (unsigned short*)(ws + 36700160);  // 16 MB
    unsigned short* Kb  = (unsigned short*)(ws + 53477376);  // 16 MB
    unsigned short* Vtb = (unsigned short*)(ws + 70254592);  // 16 MB  (total ~83 MB)

    ln_bf16<1024><<<8192, 256, 0, stream>>>(qt, gq, btq, xq);
    ln_bf16<768><<<8192, 256, 0, stream>>>(ct, gc, btc, xc);

    transpose_cast<<<dim3(32, 32), dim3(32, 8), 0, stream>>>(Wq, Wqt, 1024, 1024);
    transpose_cast<<<dim3(32, 24), dim3(32, 8), 0, stream>>>(Wk, Wkt, 768, 1024);
    transpose_cast<<<dim3(32, 24), dim3(32, 8), 0, stream>>>(Wv, Wvt, 768, 1024);
    transpose_cast<<<dim3(32, 32), dim3(32, 8), 0, stream>>>(Wo, Wot, 1024, 1024);

    gemm_bt<0><<<dim3(8, 64), 256, 0, stream>>>(xq, Wqt, bq, Qb, 1024);
    gemm_bt<0><<<dim3(8, 64), 256, 0, stream>>>(xc, Wkt, bk, Kb, 768);
    gemm_bt<1><<<dim3(8, 64), 256, 0, stream>>>(xc, Wvt, bv, Vtb, 768);

    flash_attn<<<dim3(8, 64), 512, 0, stream>>>(Qb, Kb, Vtb, xq);

    gemm_bt<2><<<dim3(8, 64), 256, 0, stream>>>(xq, Wot, bo, d_out, 1024);
}